// Round 4
// baseline (61.617 us; speedup 1.0000x reference)
//
#include <hip/hip_runtime.h>
#include <hip/hip_bf16.h>
#include <math.h>

// SpatialAxialAttention: B*T=2, H=W=16, dim=1024, HEADS=16, DIM_HEAD=64, K=144
#define BTN   2
#define NH    16
#define SEQ   256
#define DH    64
#define DIMF  1024
#define KTOP  144
#define QT    32
#define PI_F  3.14159265358979323846f

typedef _Float16 half8 __attribute__((ext_vector_type(8)));
typedef _Float16 half4v __attribute__((ext_vector_type(4)));
typedef float f32x4 __attribute__((ext_vector_type(4)));

#define GLDS(src, dst) __builtin_amdgcn_global_load_lds( \
        (const __attribute__((address_space(1))) void*)(src), \
        (__attribute__((address_space(3))) void*)(dst), 16, 0, 0)

// swizzled LDS byte offset for row r, half-element column c (chunk = 8 halves)
__device__ __forceinline__ int swz_b(int r, int c) {
    return r * 128 + (((c >> 3) ^ (r & 7)) * 16) + ((c >> 2) & 1) * 8;
}

// ---------------------------------------------------------------------------
// fp16 MFMA NT-GEMM with fused fp32->fp16 conversion in the staging path.
// 64x64 tile, BK=64, 256 threads (4 waves, 2x2 32x32 frags each).
// A path: MODE 0 = fp32 source (x), reg-staged+converted; MODE 1 = fp16
// source (attnh) via global_load_lds. B always fp32 (weights), reg-staged.
// Register prefetch of tile k+1 overlaps global latency with MFMA.
// MODE 0 epilogue: split qkv -> RoPE q,k -> fp16 (bt,head,s,d); v ->
// fp16 transposed (bt,head,d,s). MODE 1: +bias, fp32 row-major store.
// ---------------------------------------------------------------------------
template <int MODE, int Kd>
__global__ __launch_bounds__(256, 2)
void gemm_f16_kernel(const float* __restrict__ A32, const _Float16* __restrict__ A16,
                     const float* __restrict__ B32, int N,
                     _Float16* __restrict__ qb, _Float16* __restrict__ kb,
                     _Float16* __restrict__ vb,
                     const float* __restrict__ bias, float* __restrict__ out)
{
    __shared__ __align__(16) _Float16 As[64 * 64];
    __shared__ __align__(16) _Float16 Bs[64 * 64];

    const int tid  = threadIdx.x;
    const int wave = tid >> 6;
    const int lane = tid & 63;
    const int row0 = blockIdx.y * 64;
    const int col0 = blockIdx.x * 64;
    const int wr = (wave >> 1) * 32;
    const int wc = (wave & 1) * 32;

    const int sr = tid >> 4;          // 0..15 (staging row within 16-row group)
    const int sc = (tid & 15) * 4;    // 0..60 (element column, 4-wide)

    float4 areg[4], breg[4];
    const int NT = Kd / 64;

    // prologue: tile 0 -> regs
    if (MODE == 0) {
#pragma unroll
        for (int p = 0; p < 4; ++p)
            areg[p] = *(const float4*)(A32 + (size_t)(row0 + p * 16 + sr) * Kd + sc);
    }
#pragma unroll
    for (int p = 0; p < 4; ++p)
        breg[p] = *(const float4*)(B32 + (size_t)(col0 + p * 16 + sr) * Kd + sc);

    f32x4 acc[2][2] = {};

    for (int kt = 0; kt < NT; ++kt) {
        __syncthreads();
        if (MODE == 0) {
#pragma unroll
            for (int p = 0; p < 4; ++p) {
                const int r = p * 16 + sr;
                half4v h;
                h[0] = (_Float16)areg[p].x; h[1] = (_Float16)areg[p].y;
                h[2] = (_Float16)areg[p].z; h[3] = (_Float16)areg[p].w;
                *(half4v*)((char*)As + swz_b(r, sc)) = h;
            }
        } else {
#pragma unroll
            for (int h = 0; h < 2; ++h) {
                const int rbase = wave * 16 + h * 8;
                const int rA = rbase + (lane >> 3);
                GLDS(A16 + (size_t)(row0 + rA) * Kd + kt * 64 + (((lane & 7) ^ (rA & 7)) * 8),
                     As + rbase * 64);
            }
        }
#pragma unroll
        for (int p = 0; p < 4; ++p) {
            const int r = p * 16 + sr;
            half4v h;
            h[0] = (_Float16)breg[p].x; h[1] = (_Float16)breg[p].y;
            h[2] = (_Float16)breg[p].z; h[3] = (_Float16)breg[p].w;
            *(half4v*)((char*)Bs + swz_b(r, sc)) = h;
        }
        __syncthreads();

        // prefetch tile kt+1 to regs (hides under MFMA below)
        if (kt + 1 < NT) {
            const int kn = (kt + 1) * 64;
            if (MODE == 0) {
#pragma unroll
                for (int p = 0; p < 4; ++p)
                    areg[p] = *(const float4*)(A32 + (size_t)(row0 + p * 16 + sr) * Kd + kn + sc);
            }
#pragma unroll
            for (int p = 0; p < 4; ++p)
                breg[p] = *(const float4*)(B32 + (size_t)(col0 + p * 16 + sr) * Kd + kn + sc);
        }

#pragma unroll
        for (int kh = 0; kh < 2; ++kh) {
            half8 a[2], b[2];
            const int g = kh * 4 + (lane >> 4);
#pragma unroll
            for (int i = 0; i < 2; ++i) {
                const int ra = wr + i * 16 + (lane & 15);
                const int rb = wc + i * 16 + (lane & 15);
                a[i] = *(const half8*)((char*)As + ra * 128 + ((g ^ (ra & 7)) * 16));
                b[i] = *(const half8*)((char*)Bs + rb * 128 + ((g ^ (rb & 7)) * 16));
            }
#pragma unroll
            for (int i = 0; i < 2; ++i)
#pragma unroll
                for (int j = 0; j < 2; ++j)
                    acc[i][j] = __builtin_amdgcn_mfma_f32_16x16x32_f16(a[i], b[j], acc[i][j], 0, 0, 0);
        }
    }

    // C/D layout: col = lane&15, row = (lane>>4)*4 + reg
    if (MODE == 0) {
#pragma unroll
        for (int i = 0; i < 2; ++i) {
#pragma unroll
            for (int reg = 0; reg < 4; ++reg) {
                const int r  = row0 + wr + i * 16 + (lane >> 4) * 4 + reg;
                const int bt = r >> 8;
                const int s  = r & 255;
                const int hh = s >> 4;
                const int ww = s & 15;
#pragma unroll
                for (int j = 0; j < 2; ++j) {
                    const float v     = acc[i][j][reg];
                    const float other = __shfl_xor(v, 1);   // RoPE pair partner
                    const int n    = col0 + wc + j * 16 + (lane & 15);
                    const int sec  = n >> 10;       // 0=q,1=k,2=v
                    const int oi   = n & 1023;
                    const int head = oi >> 6;
                    const int d    = oi & 63;
                    if (sec == 2) {
                        vb[(((size_t)(bt * NH + head)) * DH + d) * SEQ + s] = (_Float16)v;
                    } else {
                        const int de  = d & ~1;
                        const int j2  = (de < 32) ? (de >> 1) : ((de - 32) >> 1);
                        const float pos = (de < 32) ? (-1.f + hh * (2.f / 15.f))
                                                    : (-1.f + ww * (2.f / 15.f));
                        const float f  = pos * (PI_F * (1.f + j2 * (127.f / 15.f)));
                        const float cf = __cosf(f), sf = __sinf(f);
                        const float res = (d & 1) ? (v * cf + other * sf)
                                                  : (v * cf - other * sf);
                        _Float16* dp = (sec == 0) ? qb : kb;
                        dp[(((size_t)(bt * NH + head)) * SEQ + s) * DH + d] = (_Float16)res;
                    }
                }
            }
        }
    } else {
#pragma unroll
        for (int i = 0; i < 2; ++i)
#pragma unroll
            for (int reg = 0; reg < 4; ++reg) {
                const int r = row0 + wr + i * 16 + (lane >> 4) * 4 + reg;
#pragma unroll
                for (int j = 0; j < 2; ++j) {
                    const int n = col0 + wc + j * 16 + (lane & 15);
                    out[(size_t)r * N + n] = acc[i][j][reg] + bias[n];
                }
            }
    }
}

// ---------------------------------------------------------------------------
// Dense-score top-k attention. One block per (bt, head, 32-query tile),
// 8 waves. Phase A: S = Q.K^T (MFMA, all 256 keys). Phase B: per query,
// gather 144 scalar scores from LDS, shuffle softmax, scatter-add probs
// into a dense P row (LDS atomicAdd sums duplicate indices, matching the
// reference's multiset softmax). Phase C: out = P.V (MFMA) + ontk,
// fp16 store to (bt, s, head*64+d).
// ---------------------------------------------------------------------------
__global__ __launch_bounds__(512)
void attn_dense_kernel(const _Float16* __restrict__ qh, const _Float16* __restrict__ kh,
                       const _Float16* __restrict__ vt, const int* __restrict__ topk,
                       const float* __restrict__ ontk, _Float16* __restrict__ attnh)
{
    __shared__ __align__(16) _Float16 Qs[QT * DH];      // 4 KB
    __shared__ __align__(16) _Float16 Ks[SEQ * DH];     // 32 KB
    __shared__ __align__(16) _Float16 VTs[DH * SEQ];    // 32 KB
    __shared__ __align__(16) float    Ps[QT * 260];     // 33.3 KB

    const int tid  = threadIdx.x;
    const int w    = tid >> 6;
    const int lane = tid & 63;
    const int bid  = blockIdx.x;
    const int bt   = bid >> 7;
    const int head = (bid >> 3) & 15;
    const int s0   = (bid & 7) * QT;

    const _Float16* kbase  = kh + ((size_t)(bt * NH + head)) * SEQ * DH;
    const _Float16* vtbase = vt + ((size_t)(bt * NH + head)) * DH * SEQ;
    const _Float16* qbase  = qh + (((size_t)(bt * NH + head)) * SEQ + s0) * DH;

#pragma unroll
    for (int h = 0; h < 4; ++h) {
        const int r = w * 32 + h * 8 + (lane >> 3);
        GLDS(kbase + (size_t)r * DH + (((lane & 7) ^ (r & 7)) * 8), Ks + (w * 32 + h * 8) * DH);
    }
#pragma unroll
    for (int h = 0; h < 4; ++h) {
        const int r = w * 8 + h * 2 + (lane >> 5);
        GLDS(vtbase + (size_t)r * SEQ + (((lane & 31) ^ (r & 7)) * 8), VTs + (w * 8 + h * 2) * SEQ);
    }
    if (w < 4) {
        const int r = w * 8 + (lane >> 3);
        GLDS(qbase + (size_t)r * DH + (((lane & 7) ^ (r & 7)) * 8), Qs + (w * 8) * DH);
    }
    __syncthreads();

    // Phase A: S[32][256], wave w owns key cols w*32..w*32+31
    f32x4 acc[2][2] = {};
#pragma unroll
    for (int kk = 0; kk < 2; ++kk) {
        half8 a[2], b[2];
        const int c = kk * 4 + (lane >> 4);
#pragma unroll
        for (int i = 0; i < 2; ++i) {
            const int ra = i * 16 + (lane & 15);
            const int rb = w * 32 + i * 16 + (lane & 15);
            a[i] = *(const half8*)(Qs + ra * DH + ((c ^ (ra & 7)) * 8));
            b[i] = *(const half8*)(Ks + rb * DH + ((c ^ (rb & 7)) * 8));
        }
#pragma unroll
        for (int i = 0; i < 2; ++i)
#pragma unroll
            for (int j = 0; j < 2; ++j)
                acc[i][j] = __builtin_amdgcn_mfma_f32_16x16x32_f16(a[i], b[j], acc[i][j], 0, 0, 0);
    }
#pragma unroll
    for (int i = 0; i < 2; ++i)
#pragma unroll
        for (int j = 0; j < 2; ++j)
#pragma unroll
            for (int reg = 0; reg < 4; ++reg) {
                const int row = i * 16 + (lane >> 4) * 4 + reg;
                const int col = w * 32 + j * 16 + (lane & 15);
                Ps[row * 260 + col] = acc[i][j][reg];
            }
    __syncthreads();

    // Phase B: softmax + prob scatter; wave w owns queries w*4..w*4+3
#pragma unroll
    for (int qq = 0; qq < 4; ++qq) {
        const int q = w * 4 + qq;
        const size_t gq = ((size_t)(bt * NH + head)) * SEQ + s0 + q;
        const int* idxp = topk + gq * KTOP;
        const int ki0 = idxp[lane];
        const int ki1 = idxp[lane + 64];
        const int ki2 = (lane < 16) ? idxp[lane + 128] : 0;
        const float sv0 = Ps[q * 260 + ki0] * 0.125f;
        const float sv1 = Ps[q * 260 + ki1] * 0.125f;
        const float sv2 = (lane < 16) ? Ps[q * 260 + ki2] * 0.125f : -1e30f;
        float m = fmaxf(fmaxf(sv0, sv1), sv2);
#pragma unroll
        for (int off = 32; off; off >>= 1) m = fmaxf(m, __shfl_xor(m, off));
        const float e0 = __expf(sv0 - m);
        const float e1 = __expf(sv1 - m);
        const float e2 = (lane < 16) ? __expf(sv2 - m) : 0.f;
        float z = e0 + e1 + e2;
#pragma unroll
        for (int off = 32; off; off >>= 1) z += __shfl_xor(z, off);
        const float inv = 1.f / z;
        for (int c2 = lane; c2 < 260; c2 += 64) Ps[q * 260 + c2] = 0.f;
        atomicAdd(&Ps[q * 260 + ki0], e0 * inv);
        atomicAdd(&Ps[q * 260 + ki1], e1 * inv);
        if (lane < 16) atomicAdd(&Ps[q * 260 + ki2], e2 * inv);
    }
    __syncthreads();

    // Phase C: out[32][64] = P.V ; wave w -> frag (w>>2, w&3)
    const int iw = w >> 2;
    const int jw = w & 3;
    f32x4 oacc = {};
#pragma unroll
    for (int ks = 0; ks < 8; ++ks) {
        const int ra = iw * 16 + (lane & 15);
        const float* pp = Ps + ra * 260 + ks * 32 + (lane >> 4) * 8;
        const float4 p0 = *(const float4*)pp;
        const float4 p1 = *(const float4*)(pp + 4);
        half8 af;
        af[0] = (_Float16)p0.x; af[1] = (_Float16)p0.y;
        af[2] = (_Float16)p0.z; af[3] = (_Float16)p0.w;
        af[4] = (_Float16)p1.x; af[5] = (_Float16)p1.y;
        af[6] = (_Float16)p1.z; af[7] = (_Float16)p1.w;
        const int d = jw * 16 + (lane & 15);
        const int c = ks * 4 + (lane >> 4);
        const half8 bf = *(const half8*)(VTs + d * SEQ + ((c ^ (d & 7)) * 8));
        oacc = __builtin_amdgcn_mfma_f32_16x16x32_f16(af, bf, oacc, 0, 0, 0);
    }
#pragma unroll
    for (int reg = 0; reg < 4; ++reg) {
        const int row = iw * 16 + (lane >> 4) * 4 + reg;
        const int d   = jw * 16 + (lane & 15);
        const int s   = s0 + row;
        const float v = oacc[reg] +
            ontk[(((size_t)(bt * NH + head)) * SEQ + s) * DH + d];
        attnh[((size_t)(bt * SEQ + s)) * DIMF + head * DH + d] = (_Float16)v;
    }
}

// ---------------------------------------------------------------------------
extern "C" void kernel_launch(void* const* d_in, const int* in_sizes, int n_in,
                              void* d_out, int out_size, void* d_ws, size_t ws_size,
                              hipStream_t stream) {
    const float* x     = (const float*)d_in[0];
    const float* w_qkv = (const float*)d_in[1];
    const float* w_out = (const float*)d_in[2];
    const float* b_out = (const float*)d_in[3];
    const float* ontk  = (const float*)d_in[4];
    const int*   topk  = (const int*)d_in[5];
    float* out = (float*)d_out;

    const size_t QE = (size_t)BTN * NH * SEQ * DH;   // 524288

    _Float16* attnh = (_Float16*)d_ws;               // 512x1024 fp16
    _Float16* qhb   = attnh + (size_t)512 * 1024;
    _Float16* khb   = qhb + QE;
    _Float16* vtb   = khb + QE;

    // 1) qkv projection (fp32 in, fused cvt) + RoPE -> fp16 q,k; v^T
    gemm_f16_kernel<0, DIMF><<<dim3(3072 / 64, 512 / 64), 256, 0, stream>>>(
        x, nullptr, w_qkv, 3072, qhb, khb, vtb, nullptr, nullptr);

    // 2) dense-score top-k attention
    attn_dense_kernel<<<BTN * NH * (SEQ / QT), 512, 0, stream>>>(
        qhb, khb, vtb, topk, ontk, attnh);

    // 3) output projection (fp16 A via gload_lds, fp32 w_out fused cvt) + bias
    gemm_f16_kernel<1, DIMF><<<dim3(1024 / 64, 512 / 64), 256, 0, stream>>>(
        nullptr, attnh, w_out, 1024, nullptr, nullptr, nullptr, b_out, out);
}

// Round 5
// 49.607 us; speedup vs baseline: 1.2421x; 1.2421x over previous
//
#include <hip/hip_runtime.h>
#include <hip/hip_bf16.h>
#include <math.h>

// SpatialAxialAttention: B*T=2, H=W=16, dim=1024, HEADS=16, DIM_HEAD=64, K=144
#define BTN   2
#define NH    16
#define SEQ   256
#define DH    64
#define DIMF  1024
#define KTOP  144
#define QT    32
#define PI_F  3.14159265358979323846f

typedef _Float16 half8 __attribute__((ext_vector_type(8)));
typedef _Float16 half4v __attribute__((ext_vector_type(4)));
typedef float f32x4 __attribute__((ext_vector_type(4)));

#define GLDS(src, dst) __builtin_amdgcn_global_load_lds( \
        (const __attribute__((address_space(1))) void*)(src), \
        (__attribute__((address_space(3))) void*)(dst), 16, 0, 0)

// ---------------------------------------------------------------------------
// fp32 -> fp16 conversion for x, w_qkv, w_out
// ---------------------------------------------------------------------------
#define N0Q (524288 / 4)
#define N1Q (3145728 / 4)
#define N2Q (1048576 / 4)
__global__ __launch_bounds__(256)
void cvt3_kernel(const float* __restrict__ a, const float* __restrict__ b,
                 const float* __restrict__ c,
                 _Float16* __restrict__ da, _Float16* __restrict__ db,
                 _Float16* __restrict__ dc)
{
    int q = blockIdx.x * 256 + threadIdx.x;
    const float* s; _Float16* d; int off;
    if (q < N0Q)            { s = a; d = da; off = q; }
    else if (q < N0Q + N1Q) { s = b; d = db; off = q - N0Q; }
    else                    { s = c; d = dc; off = q - (N0Q + N1Q); }
    const float4 v = *(const float4*)(s + (size_t)off * 4);
    half4v h;
    h[0] = (_Float16)v.x; h[1] = (_Float16)v.y;
    h[2] = (_Float16)v.z; h[3] = (_Float16)v.w;
    *(half4v*)(d + (size_t)off * 4) = h;
}

// ---------------------------------------------------------------------------
// fp16 MFMA NT-GEMM (64x64 tile, BK=64, 4 waves, 2x2 32x32 frags each),
// global_load_lds staging with XOR chunk swizzle (round-3 verified version).
// MODE 0: epilogue splits qkv, RoPE on q,k -> fp16 (bt,head,s,d);
//         v -> fp16 TRANSPOSED (bt,head,d,s). MODE 1: +bias fp32 store.
// ---------------------------------------------------------------------------
template <int MODE, int Kd>
__global__ __launch_bounds__(256)
void gemm_f16_kernel(const _Float16* __restrict__ A, const _Float16* __restrict__ B,
                     int N,
                     _Float16* __restrict__ qb, _Float16* __restrict__ kb,
                     _Float16* __restrict__ vb,
                     const float* __restrict__ bias, float* __restrict__ out)
{
    __shared__ __align__(16) _Float16 As[64 * 64];
    __shared__ __align__(16) _Float16 Bs[64 * 64];

    const int tid  = threadIdx.x;
    const int wave = tid >> 6;
    const int lane = tid & 63;
    const int row0 = blockIdx.y * 64;
    const int col0 = blockIdx.x * 64;
    const int wr = (wave >> 1) * 32;
    const int wc = (wave & 1) * 32;
    const int rl = lane >> 3;
    const int cl = lane & 7;

    f32x4 acc[2][2] = {};

    for (int kt = 0; kt < Kd; kt += 64) {
        __syncthreads();
#pragma unroll
        for (int h = 0; h < 2; ++h) {
            const int rbase = wave * 16 + h * 8;
            const int rA = rbase + rl;
            const _Float16* srcA = A + (size_t)(row0 + rA) * Kd + kt + ((cl ^ (rA & 7)) * 8);
            const _Float16* srcB = B + (size_t)(col0 + rA) * Kd + kt + ((cl ^ (rA & 7)) * 8);
            GLDS(srcA, As + rbase * 64);
            GLDS(srcB, Bs + rbase * 64);
        }
        __syncthreads();

#pragma unroll
        for (int kh = 0; kh < 2; ++kh) {
            half8 a[2], b[2];
            const int g = kh * 4 + (lane >> 4);
#pragma unroll
            for (int i = 0; i < 2; ++i) {
                const int ra = wr + i * 16 + (lane & 15);
                const int rb = wc + i * 16 + (lane & 15);
                a[i] = *(const half8*)(As + ra * 64 + ((g ^ (ra & 7)) * 8));
                b[i] = *(const half8*)(Bs + rb * 64 + ((g ^ (rb & 7)) * 8));
            }
#pragma unroll
            for (int i = 0; i < 2; ++i)
#pragma unroll
                for (int j = 0; j < 2; ++j)
                    acc[i][j] = __builtin_amdgcn_mfma_f32_16x16x32_f16(a[i], b[j], acc[i][j], 0, 0, 0);
        }
    }

    // C/D layout: col = lane&15, row = (lane>>4)*4 + reg
    if (MODE == 0) {
#pragma unroll
        for (int i = 0; i < 2; ++i) {
#pragma unroll
            for (int reg = 0; reg < 4; ++reg) {
                const int r  = row0 + wr + i * 16 + (lane >> 4) * 4 + reg;
                const int bt = r >> 8;
                const int s  = r & 255;
                const int hh = s >> 4;
                const int ww = s & 15;
#pragma unroll
                for (int j = 0; j < 2; ++j) {
                    const float v     = acc[i][j][reg];
                    const float other = __shfl_xor(v, 1);   // RoPE pair partner
                    const int n    = col0 + wc + j * 16 + (lane & 15);
                    const int sec  = n >> 10;       // 0=q,1=k,2=v
                    const int oi   = n & 1023;
                    const int head = oi >> 6;
                    const int d    = oi & 63;
                    if (sec == 2) {
                        vb[(((size_t)(bt * NH + head)) * DH + d) * SEQ + s] = (_Float16)v;
                    } else {
                        const int de  = d & ~1;
                        const int j2  = (de < 32) ? (de >> 1) : ((de - 32) >> 1);
                        const float pos = (de < 32) ? (-1.f + hh * (2.f / 15.f))
                                                    : (-1.f + ww * (2.f / 15.f));
                        const float f  = pos * (PI_F * (1.f + j2 * (127.f / 15.f)));
                        const float cf = __cosf(f), sf = __sinf(f);
                        const float res = (d & 1) ? (v * cf + other * sf)
                                                  : (v * cf - other * sf);
                        _Float16* dp = (sec == 0) ? qb : kb;
                        dp[(((size_t)(bt * NH + head)) * SEQ + s) * DH + d] = (_Float16)res;
                    }
                }
            }
        }
    } else {
#pragma unroll
        for (int i = 0; i < 2; ++i)
#pragma unroll
            for (int reg = 0; reg < 4; ++reg) {
                const int r = row0 + wr + i * 16 + (lane >> 4) * 4 + reg;
#pragma unroll
                for (int j = 0; j < 2; ++j) {
                    const int n = col0 + wc + j * 16 + (lane & 15);
                    out[(size_t)r * N + n] = acc[i][j][reg] + bias[n];
                }
            }
    }
}

// ---------------------------------------------------------------------------
// Register-resident dense-score top-k attention. One block per
// (bt, head, 32-query tile), 8 waves, NO K/V/Q LDS staging:
//  - all global loads (topk idx, ontk, V b-frags, Q/K a/b-frags) issued at
//    kernel entry; latency hides under phase A/B.
//  - LDS holds only the 32x256 score/prob matrix, col-swizzled
//    (c ^= (r&7)<<2) to make PV a-frag float4 reads ~conflict-free.
// Phase A: S = Q.K^T (8 MFMA/wave, wave w owns key cols w*32..+31).
// Phase B: wave w owns queries 4w..4w+3: gather 144 scalar scores, shuffle
//    softmax, zero row, scatter-add probs (LDS atomicAdd sums duplicates).
// Phase C: out = P.V (8 MFMA/wave, frag (w>>2, w&3)) + ontk -> fp16
//    (bt, s, head*64+d).
// ---------------------------------------------------------------------------
__global__ __launch_bounds__(512)
void attn_reg_kernel(const _Float16* __restrict__ qh, const _Float16* __restrict__ kh,
                     const _Float16* __restrict__ vt, const int* __restrict__ topk,
                     const float* __restrict__ ontk, _Float16* __restrict__ attnh)
{
    __shared__ __align__(16) float Ps[QT * 256];   // 32 KB

    const int tid  = threadIdx.x;
    const int w    = tid >> 6;
    const int lane = tid & 63;
    const int bid  = blockIdx.x;
    const int bt   = bid >> 7;
    const int head = (bid >> 3) & 15;
    const int s0   = (bid & 7) * QT;
    const int bh   = bt * NH + head;
    const int iw   = w >> 2;
    const int jw   = w & 3;

    // ---- prefetch topk indices (wave w owns queries 4w..4w+3) ----
    int ki0[4], ki1[4], ki2[4];
#pragma unroll
    for (int qq = 0; qq < 4; ++qq) {
        const int* idxp = topk + ((size_t)bh * SEQ + s0 + w * 4 + qq) * KTOP;
        ki0[qq] = idxp[lane];
        ki1[qq] = idxp[lane + 64];
        ki2[qq] = idxp[(lane < 16) ? (lane + 128) : lane];
    }
    // ---- prefetch ontk (epilogue) ----
    float on[4];
#pragma unroll
    for (int reg = 0; reg < 4; ++reg) {
        const int row = iw * 16 + (lane >> 4) * 4 + reg;
        on[reg] = ontk[((size_t)bh * SEQ + s0 + row) * DH + jw * 16 + (lane & 15)];
    }
    // ---- prefetch V b-frags (phase C): row d = jw*16+(lane&15) ----
    half8 bv[8];
    {
        const _Float16* vrow = vt + ((size_t)bh * DH + jw * 16 + (lane & 15)) * SEQ
                                  + (lane >> 4) * 8;
#pragma unroll
        for (int ks = 0; ks < 8; ++ks)
            bv[ks] = *(const half8*)(vrow + ks * 32);
    }
    // ---- Q a-frags / K b-frags ----
    half8 aq[2][2], bk[2][2];
#pragma unroll
    for (int kk = 0; kk < 2; ++kk) {
        const int c8 = (kk * 4 + (lane >> 4)) * 8;
#pragma unroll
        for (int i = 0; i < 2; ++i) {
            aq[kk][i] = *(const half8*)(qh + ((size_t)bh * SEQ + s0 + i * 16 + (lane & 15)) * DH + c8);
            bk[kk][i] = *(const half8*)(kh + ((size_t)bh * SEQ + w * 32 + i * 16 + (lane & 15)) * DH + c8);
        }
    }

    // ---- Phase A: S[32][256] ----
    f32x4 acc[2][2] = {};
#pragma unroll
    for (int kk = 0; kk < 2; ++kk)
#pragma unroll
        for (int i = 0; i < 2; ++i)
#pragma unroll
            for (int j = 0; j < 2; ++j)
                acc[i][j] = __builtin_amdgcn_mfma_f32_16x16x32_f16(aq[kk][i], bk[kk][j], acc[i][j], 0, 0, 0);
#pragma unroll
    for (int i = 0; i < 2; ++i)
#pragma unroll
        for (int j = 0; j < 2; ++j)
#pragma unroll
            for (int reg = 0; reg < 4; ++reg) {
                const int row = i * 16 + (lane >> 4) * 4 + reg;
                const int col = w * 32 + j * 16 + (lane & 15);
                Ps[row * 256 + (col ^ ((row & 7) << 2))] = acc[i][j][reg];
            }
    __syncthreads();

    // ---- Phase B: softmax + prob scatter ----
#pragma unroll
    for (int qq = 0; qq < 4; ++qq) {
        const int q  = w * 4 + qq;
        const int sw = (q & 7) << 2;
        float* prow  = Ps + q * 256;
        const float sv0 = prow[ki0[qq] ^ sw] * 0.125f;
        const float sv1 = prow[ki1[qq] ^ sw] * 0.125f;
        const float sv2 = (lane < 16) ? prow[ki2[qq] ^ sw] * 0.125f : -1e30f;
        float m = fmaxf(fmaxf(sv0, sv1), sv2);
#pragma unroll
        for (int off = 32; off; off >>= 1) m = fmaxf(m, __shfl_xor(m, off));
        const float e0 = __expf(sv0 - m);
        const float e1 = __expf(sv1 - m);
        const float e2 = (lane < 16) ? __expf(sv2 - m) : 0.f;
        float z = e0 + e1 + e2;
#pragma unroll
        for (int off = 32; off; off >>= 1) z += __shfl_xor(z, off);
        const float inv = 1.f / z;
        // zero the row (swizzle is a per-row bijection -> linear zero is fine)
#pragma unroll
        for (int c2 = 0; c2 < 4; ++c2) prow[lane + c2 * 64] = 0.f;
        atomicAdd(&prow[ki0[qq] ^ sw], e0 * inv);
        atomicAdd(&prow[ki1[qq] ^ sw], e1 * inv);
        if (lane < 16) atomicAdd(&prow[ki2[qq] ^ sw], e2 * inv);
    }
    __syncthreads();

    // ---- Phase C: out[32][64] = P.V ; wave w -> frag (iw, jw) ----
    f32x4 oacc = {};
#pragma unroll
    for (int ks = 0; ks < 8; ++ks) {
        const int ra = iw * 16 + (lane & 15);
        const int b0 = ks * 32 + (lane >> 4) * 8;
        const int sw = (ra & 7) << 2;
        const float4 p0 = *(const float4*)(Ps + ra * 256 + (b0 ^ sw));
        const float4 p1 = *(const float4*)(Ps + ra * 256 + ((b0 + 4) ^ sw));
        half8 af;
        af[0] = (_Float16)p0.x; af[1] = (_Float16)p0.y;
        af[2] = (_Float16)p0.z; af[3] = (_Float16)p0.w;
        af[4] = (_Float16)p1.x; af[5] = (_Float16)p1.y;
        af[6] = (_Float16)p1.z; af[7] = (_Float16)p1.w;
        oacc = __builtin_amdgcn_mfma_f32_16x16x32_f16(af, bv[ks], oacc, 0, 0, 0);
    }
#pragma unroll
    for (int reg = 0; reg < 4; ++reg) {
        const int row = iw * 16 + (lane >> 4) * 4 + reg;
        const int d   = jw * 16 + (lane & 15);
        const int s   = s0 + row;
        attnh[((size_t)(bt * SEQ + s)) * DIMF + head * DH + d] = (_Float16)(oacc[reg] + on[reg]);
    }
}

// ---------------------------------------------------------------------------
extern "C" void kernel_launch(void* const* d_in, const int* in_sizes, int n_in,
                              void* d_out, int out_size, void* d_ws, size_t ws_size,
                              hipStream_t stream) {
    const float* x     = (const float*)d_in[0];
    const float* w_qkv = (const float*)d_in[1];
    const float* w_out = (const float*)d_in[2];
    const float* b_out = (const float*)d_in[3];
    const float* ontk  = (const float*)d_in[4];
    const int*   topk  = (const int*)d_in[5];
    float* out = (float*)d_out;

    const size_t QE = (size_t)BTN * NH * SEQ * DH;   // 524288

    _Float16* xh    = (_Float16*)d_ws;
    _Float16* wqh   = xh + 524288;
    _Float16* woh   = wqh + 3145728;
    _Float16* attnh = woh + 1048576;
    _Float16* qhb   = attnh + QE;
    _Float16* khb   = qhb + QE;
    _Float16* vtb   = khb + QE;

    // 1) fp32->fp16 inputs
    cvt3_kernel<<<(N0Q + N1Q + N2Q) / 256, 256, 0, stream>>>(x, w_qkv, w_out, xh, wqh, woh);

    // 2) qkv projection + RoPE -> fp16 q,k (bt,head,s,d); v^T (bt,head,d,s)
    gemm_f16_kernel<0, DIMF><<<dim3(3072 / 64, 512 / 64), 256, 0, stream>>>(
        xh, wqh, 3072, qhb, khb, vtb, nullptr, nullptr);

    // 3) register-resident dense-score top-k attention
    attn_reg_kernel<<<BTN * NH * (SEQ / QT), 512, 0, stream>>>(
        qhb, khb, vtb, topk, ontk, attnh);

    // 4) output projection + bias
    gemm_f16_kernel<1, DIMF><<<dim3(1024 / 64, 512 / 64), 256, 0, stream>>>(
        attnh, woh, 1024, nullptr, nullptr, nullptr, b_out, out);
}

// Round 6
// 49.361 us; speedup vs baseline: 1.2483x; 1.0050x over previous
//
#include <hip/hip_runtime.h>
#include <hip/hip_bf16.h>
#include <math.h>

// SpatialAxialAttention: B*T=2, H=W=16, dim=1024, HEADS=16, DIM_HEAD=64, K=144
#define BTN   2
#define NH    16
#define SEQ   256
#define DH    64
#define DIMF  1024
#define KTOP  144
#define QT    16
#define PI_F  3.14159265358979323846f

typedef _Float16 half8 __attribute__((ext_vector_type(8)));
typedef _Float16 half4v __attribute__((ext_vector_type(4)));
typedef float f32x4 __attribute__((ext_vector_type(4)));

#define GLDS(src, dst) __builtin_amdgcn_global_load_lds( \
        (const __attribute__((address_space(1))) void*)(src), \
        (__attribute__((address_space(3))) void*)(dst), 16, 0, 0)

// ---------------------------------------------------------------------------
// fp32 -> fp16 conversion for x, w_qkv, w_out
// ---------------------------------------------------------------------------
#define N0Q (524288 / 4)
#define N1Q (3145728 / 4)
#define N2Q (1048576 / 4)
__global__ __launch_bounds__(256)
void cvt3_kernel(const float* __restrict__ a, const float* __restrict__ b,
                 const float* __restrict__ c,
                 _Float16* __restrict__ da, _Float16* __restrict__ db,
                 _Float16* __restrict__ dc)
{
    int q = blockIdx.x * 256 + threadIdx.x;
    const float* s; _Float16* d; int off;
    if (q < N0Q)            { s = a; d = da; off = q; }
    else if (q < N0Q + N1Q) { s = b; d = db; off = q - N0Q; }
    else                    { s = c; d = dc; off = q - (N0Q + N1Q); }
    const float4 v = *(const float4*)(s + (size_t)off * 4);
    half4v h;
    h[0] = (_Float16)v.x; h[1] = (_Float16)v.y;
    h[2] = (_Float16)v.z; h[3] = (_Float16)v.w;
    *(half4v*)(d + (size_t)off * 4) = h;
}

// ---------------------------------------------------------------------------
// fp16 MFMA NT-GEMM (64x64 tile, BK=64, 4 waves, 2x2 32x32 frags each),
// global_load_lds staging with XOR chunk swizzle (round-3 verified version).
// MODE 0: epilogue splits qkv, RoPE on q,k -> fp16 (bt,head,s,d);
//         v -> fp16 TRANSPOSED (bt,head,d,s). MODE 1: +bias fp32 store.
// ---------------------------------------------------------------------------
template <int MODE, int Kd>
__global__ __launch_bounds__(256)
void gemm_f16_kernel(const _Float16* __restrict__ A, const _Float16* __restrict__ B,
                     int N,
                     _Float16* __restrict__ qb, _Float16* __restrict__ kb,
                     _Float16* __restrict__ vb,
                     const float* __restrict__ bias, float* __restrict__ out)
{
    __shared__ __align__(16) _Float16 As[64 * 64];
    __shared__ __align__(16) _Float16 Bs[64 * 64];

    const int tid  = threadIdx.x;
    const int wave = tid >> 6;
    const int lane = tid & 63;
    const int row0 = blockIdx.y * 64;
    const int col0 = blockIdx.x * 64;
    const int wr = (wave >> 1) * 32;
    const int wc = (wave & 1) * 32;
    const int rl = lane >> 3;
    const int cl = lane & 7;

    f32x4 acc[2][2] = {};

    for (int kt = 0; kt < Kd; kt += 64) {
        __syncthreads();
#pragma unroll
        for (int h = 0; h < 2; ++h) {
            const int rbase = wave * 16 + h * 8;
            const int rA = rbase + rl;
            const _Float16* srcA = A + (size_t)(row0 + rA) * Kd + kt + ((cl ^ (rA & 7)) * 8);
            const _Float16* srcB = B + (size_t)(col0 + rA) * Kd + kt + ((cl ^ (rA & 7)) * 8);
            GLDS(srcA, As + rbase * 64);
            GLDS(srcB, Bs + rbase * 64);
        }
        __syncthreads();

#pragma unroll
        for (int kh = 0; kh < 2; ++kh) {
            half8 a[2], b[2];
            const int g = kh * 4 + (lane >> 4);
#pragma unroll
            for (int i = 0; i < 2; ++i) {
                const int ra = wr + i * 16 + (lane & 15);
                const int rb = wc + i * 16 + (lane & 15);
                a[i] = *(const half8*)(As + ra * 64 + ((g ^ (ra & 7)) * 8));
                b[i] = *(const half8*)(Bs + rb * 64 + ((g ^ (rb & 7)) * 8));
            }
#pragma unroll
            for (int i = 0; i < 2; ++i)
#pragma unroll
                for (int j = 0; j < 2; ++j)
                    acc[i][j] = __builtin_amdgcn_mfma_f32_16x16x32_f16(a[i], b[j], acc[i][j], 0, 0, 0);
        }
    }

    // C/D layout: col = lane&15, row = (lane>>4)*4 + reg
    if (MODE == 0) {
#pragma unroll
        for (int i = 0; i < 2; ++i) {
#pragma unroll
            for (int reg = 0; reg < 4; ++reg) {
                const int r  = row0 + wr + i * 16 + (lane >> 4) * 4 + reg;
                const int bt = r >> 8;
                const int s  = r & 255;
                const int hh = s >> 4;
                const int ww = s & 15;
#pragma unroll
                for (int j = 0; j < 2; ++j) {
                    const float v     = acc[i][j][reg];
                    const float other = __shfl_xor(v, 1);   // RoPE pair partner
                    const int n    = col0 + wc + j * 16 + (lane & 15);
                    const int sec  = n >> 10;       // 0=q,1=k,2=v
                    const int oi   = n & 1023;
                    const int head = oi >> 6;
                    const int d    = oi & 63;
                    if (sec == 2) {
                        vb[(((size_t)(bt * NH + head)) * DH + d) * SEQ + s] = (_Float16)v;
                    } else {
                        const int de  = d & ~1;
                        const int j2  = (de < 32) ? (de >> 1) : ((de - 32) >> 1);
                        const float pos = (de < 32) ? (-1.f + hh * (2.f / 15.f))
                                                    : (-1.f + ww * (2.f / 15.f));
                        const float f  = pos * (PI_F * (1.f + j2 * (127.f / 15.f)));
                        const float cf = __cosf(f), sf = __sinf(f);
                        const float res = (d & 1) ? (v * cf + other * sf)
                                                  : (v * cf - other * sf);
                        _Float16* dp = (sec == 0) ? qb : kb;
                        dp[(((size_t)(bt * NH + head)) * SEQ + s) * DH + d] = (_Float16)res;
                    }
                }
            }
        }
    } else {
#pragma unroll
        for (int i = 0; i < 2; ++i)
#pragma unroll
            for (int reg = 0; reg < 4; ++reg) {
                const int r = row0 + wr + i * 16 + (lane >> 4) * 4 + reg;
#pragma unroll
                for (int j = 0; j < 2; ++j) {
                    const int n = col0 + wc + j * 16 + (lane & 15);
                    out[(size_t)r * N + n] = acc[i][j][reg] + bias[n];
                }
            }
    }
}

// ---------------------------------------------------------------------------
// Register-resident dense-score top-k attention, HIGH-OCCUPANCY version:
// one block per (bt, head, 16-query tile) -> 512 blocks x 4 waves (256 thr),
// ~2-3 blocks/CU so independent blocks hide each other's latency.
//  Phase A: S[16][256] = Q.K^T; wave w owns key cols w*64..w*64+63 (8 MFMA).
//  Phase B: wave w owns queries 4w..4w+3: gather 144 scalar scores from the
//    swizzled LDS row, shuffle softmax, zero row, scatter-add probs
//    (LDS atomicAdd sums duplicate indices = reference multiset softmax).
//  Phase C: out[16][64] = P.V; wave w owns d-cols w*16..w*16+15 (8 MFMA),
//    + ontk, fp16 store to (bt, s, head*64+d).
// Q/K frags issued first (phase-A critical); topk/V/ontk loads stay in
// flight under phase A via counted vmcnt.
// ---------------------------------------------------------------------------
__global__ __launch_bounds__(256)
void attn_reg16_kernel(const _Float16* __restrict__ qh, const _Float16* __restrict__ kh,
                       const _Float16* __restrict__ vt, const int* __restrict__ topk,
                       const float* __restrict__ ontk, _Float16* __restrict__ attnh)
{
    __shared__ __align__(16) float Ps[QT * 256];   // 16 KB

    const int tid  = threadIdx.x;
    const int w    = tid >> 6;
    const int lane = tid & 63;
    const int bid  = blockIdx.x;
    const int bt   = bid >> 8;
    const int head = (bid >> 4) & 15;
    const int s0   = (bid & 15) * QT;
    const int bh   = bt * NH + head;

    // ---- Q a-frags / K b-frags FIRST (phase A critical path) ----
    half8 aq[2], bk[2][4];
#pragma unroll
    for (int kk = 0; kk < 2; ++kk) {
        const int c8 = (kk * 4 + (lane >> 4)) * 8;
        aq[kk] = *(const half8*)(qh + ((size_t)bh * SEQ + s0 + (lane & 15)) * DH + c8);
#pragma unroll
        for (int j = 0; j < 4; ++j)
            bk[kk][j] = *(const half8*)(kh + ((size_t)bh * SEQ + w * 64 + j * 16 + (lane & 15)) * DH + c8);
    }
    // ---- topk indices (wave w owns queries 4w..4w+3) ----
    int ki0[4], ki1[4], ki2[4];
#pragma unroll
    for (int qq = 0; qq < 4; ++qq) {
        const int* idxp = topk + ((size_t)bh * SEQ + s0 + w * 4 + qq) * KTOP;
        ki0[qq] = idxp[lane];
        ki1[qq] = idxp[lane + 64];
        ki2[qq] = idxp[(lane < 16) ? (lane + 128) : lane];
    }
    // ---- V b-frags (phase C): row d = w*16+(lane&15) ----
    half8 bv[8];
    {
        const _Float16* vrow = vt + ((size_t)bh * DH + w * 16 + (lane & 15)) * SEQ
                                  + (lane >> 4) * 8;
#pragma unroll
        for (int ks = 0; ks < 8; ++ks)
            bv[ks] = *(const half8*)(vrow + ks * 32);
    }
    // ---- ontk (epilogue) ----
    float on[4];
#pragma unroll
    for (int reg = 0; reg < 4; ++reg) {
        const int row = (lane >> 4) * 4 + reg;
        on[reg] = ontk[((size_t)bh * SEQ + s0 + row) * DH + w * 16 + (lane & 15)];
    }

    // ---- Phase A: S[16][256] ----
    f32x4 acc[4] = {};
#pragma unroll
    for (int kk = 0; kk < 2; ++kk)
#pragma unroll
        for (int j = 0; j < 4; ++j)
            acc[j] = __builtin_amdgcn_mfma_f32_16x16x32_f16(aq[kk], bk[kk][j], acc[j], 0, 0, 0);
#pragma unroll
    for (int j = 0; j < 4; ++j)
#pragma unroll
        for (int reg = 0; reg < 4; ++reg) {
            const int row = (lane >> 4) * 4 + reg;
            const int col = w * 64 + j * 16 + (lane & 15);
            Ps[row * 256 + (col ^ ((row & 7) << 2))] = acc[j][reg];
        }
    __syncthreads();

    // ---- Phase B: softmax + prob scatter ----
#pragma unroll
    for (int qq = 0; qq < 4; ++qq) {
        const int q  = w * 4 + qq;
        const int sw = (q & 7) << 2;
        float* prow  = Ps + q * 256;
        const float sv0 = prow[ki0[qq] ^ sw] * 0.125f;
        const float sv1 = prow[ki1[qq] ^ sw] * 0.125f;
        const float sv2 = (lane < 16) ? prow[ki2[qq] ^ sw] * 0.125f : -1e30f;
        float m = fmaxf(fmaxf(sv0, sv1), sv2);
#pragma unroll
        for (int off = 32; off; off >>= 1) m = fmaxf(m, __shfl_xor(m, off));
        const float e0 = __expf(sv0 - m);
        const float e1 = __expf(sv1 - m);
        const float e2 = (lane < 16) ? __expf(sv2 - m) : 0.f;
        float z = e0 + e1 + e2;
#pragma unroll
        for (int off = 32; off; off >>= 1) z += __shfl_xor(z, off);
        const float inv = 1.f / z;
        // zero the row (swizzle is a per-row bijection -> linear zero is fine)
#pragma unroll
        for (int c2 = 0; c2 < 4; ++c2) prow[lane + c2 * 64] = 0.f;
        atomicAdd(&prow[ki0[qq] ^ sw], e0 * inv);
        atomicAdd(&prow[ki1[qq] ^ sw], e1 * inv);
        if (lane < 16) atomicAdd(&prow[ki2[qq] ^ sw], e2 * inv);
    }
    __syncthreads();

    // ---- Phase C: out[16][64] = P.V ; wave w owns d-cols w*16..+15 ----
    f32x4 oacc = {};
#pragma unroll
    for (int ks = 0; ks < 8; ++ks) {
        const int ra = lane & 15;
        const int b0 = ks * 32 + (lane >> 4) * 8;
        const int sw = (ra & 7) << 2;
        const float4 p0 = *(const float4*)(Ps + ra * 256 + (b0 ^ sw));
        const float4 p1 = *(const float4*)(Ps + ra * 256 + ((b0 + 4) ^ sw));
        half8 af;
        af[0] = (_Float16)p0.x; af[1] = (_Float16)p0.y;
        af[2] = (_Float16)p0.z; af[3] = (_Float16)p0.w;
        af[4] = (_Float16)p1.x; af[5] = (_Float16)p1.y;
        af[6] = (_Float16)p1.z; af[7] = (_Float16)p1.w;
        oacc = __builtin_amdgcn_mfma_f32_16x16x32_f16(af, bv[ks], oacc, 0, 0, 0);
    }
#pragma unroll
    for (int reg = 0; reg < 4; ++reg) {
        const int row = (lane >> 4) * 4 + reg;
        const int d   = w * 16 + (lane & 15);
        const int s   = s0 + row;
        attnh[((size_t)(bt * SEQ + s)) * DIMF + head * DH + d] = (_Float16)(oacc[reg] + on[reg]);
    }
}

// ---------------------------------------------------------------------------
extern "C" void kernel_launch(void* const* d_in, const int* in_sizes, int n_in,
                              void* d_out, int out_size, void* d_ws, size_t ws_size,
                              hipStream_t stream) {
    const float* x     = (const float*)d_in[0];
    const float* w_qkv = (const float*)d_in[1];
    const float* w_out = (const float*)d_in[2];
    const float* b_out = (const float*)d_in[3];
    const float* ontk  = (const float*)d_in[4];
    const int*   topk  = (const int*)d_in[5];
    float* out = (float*)d_out;

    const size_t QE = (size_t)BTN * NH * SEQ * DH;   // 524288

    _Float16* xh    = (_Float16*)d_ws;
    _Float16* wqh   = xh + 524288;
    _Float16* woh   = wqh + 3145728;
    _Float16* attnh = woh + 1048576;
    _Float16* qhb   = attnh + QE;
    _Float16* khb   = qhb + QE;
    _Float16* vtb   = khb + QE;

    // 1) fp32->fp16 inputs
    cvt3_kernel<<<(N0Q + N1Q + N2Q) / 256, 256, 0, stream>>>(x, w_qkv, w_out, xh, wqh, woh);

    // 2) qkv projection + RoPE -> fp16 q,k (bt,head,s,d); v^T (bt,head,d,s)
    gemm_f16_kernel<0, DIMF><<<dim3(3072 / 64, 512 / 64), 256, 0, stream>>>(
        xh, wqh, 3072, qhb, khb, vtb, nullptr, nullptr);

    // 3) high-occupancy register-resident top-k attention (512 blocks)
    attn_reg16_kernel<<<BTN * NH * (SEQ / QT), 256, 0, stream>>>(
        qhb, khb, vtb, topk, ontk, attnh);

    // 4) output projection + bias
    gemm_f16_kernel<1, DIMF><<<dim3(1024 / 64, 512 / 64), 256, 0, stream>>>(
        attnh, woh, 1024, nullptr, nullptr, nullptr, b_out, out);
}